// Round 7
// baseline (232.699 us; speedup 1.0000x reference)
//
#include <hip/hip_runtime.h>

// HyperedgeMeanAggregator: out[h,:] = mean of embed[node_idx[e],:] over the
// contiguous run of entries e with seg_ids[e]==h (seg_ids sorted).
//
// Round 7 = Round 6 with the compile fix (NT store needs a clang ext-vector,
// not HIP's ushort4 class). Model (validated R5):
//   time(gather) = random-128B-line fetch volume / ~3.3 TB/s
//   -> bf16 staging halves the volume (R5: 130 -> 60.5 us, FETCH 390 -> 190 MB).
//   fp8 would halve again but absmax ~ 2*eps(fmt) -> ~0.125 > 0.0209 threshold.
// This round: fuse seg_offsets into the convert dispatch (removes one
// serialized launch), widen main loop to 16 in-flight row-gathers.

#define D 128

typedef float f4 __attribute__((ext_vector_type(4)));
typedef unsigned short us4 __attribute__((ext_vector_type(4)));

// Fused prologue: blocks [0, nb_cvt) convert fp32->bf16 (4 elems/thread);
// blocks [nb_cvt, nb_cvt+nb_off) compute segment offsets. Independent work.
__global__ __launch_bounds__(256)
void prologue_kernel(const float* __restrict__ src,
                     unsigned short* __restrict__ dst, int n4, int nb_cvt,
                     const int* __restrict__ seg, int E, int H,
                     int* __restrict__ off) {
    if ((int)blockIdx.x < nb_cvt) {
        const int i = blockIdx.x * 256 + threadIdx.x;
        if (i >= n4) return;
        const f4 v = ((const f4*)src)[i];
        union { float f; unsigned u; } c;
        us4 r;
#define CVT(K, X) c.f = (X); \
        r[K] = (unsigned short)((c.u + 0x7fffu + ((c.u >> 16) & 1u)) >> 16);
        CVT(0, v.x) CVT(1, v.y) CVT(2, v.z) CVT(3, v.w)
#undef CVT
        __builtin_nontemporal_store(r, (us4*)dst + i);
    } else {
        const int e = (blockIdx.x - nb_cvt) * 256 + threadIdx.x;
        if (e >= E) return;
        const int s = seg[e];
        const int prev = (e == 0) ? -1 : seg[e - 1];
        for (int h = prev + 1; h <= s; ++h) off[h] = e;
        if (e == E - 1) {
            for (int h = s + 1; h <= H; ++h) off[h] = E;
        }
    }
}

__device__ __forceinline__ float bf16_lo(unsigned u) {
    union { unsigned u; float f; } c; c.u = u << 16; return c.f;
}
__device__ __forceinline__ float bf16_hi(unsigned u) {
    union { unsigned u; float f; } c; c.u = u & 0xffff0000u; return c.f;
}

// Main gather over the bf16 staged table. One wave per segment.
// lane&31 owns bf16 dims [4c..4c+3] (uint2 = 8B); 32 lanes x 8B = 256B = one
// row = exactly 2 cache lines; lane>>5 picks which of 2 rows per load instr;
// 16 load instrs = 32 entries (one avg segment) in flight per wave.
__global__ __launch_bounds__(256)
void hyperedge_mean_bf16(const unsigned short* __restrict__ table,
                         const int* __restrict__ node_idx,
                         const int* __restrict__ off,
                         float* __restrict__ out,
                         int H) {
    const int wave = threadIdx.x >> 6;
    const int h    = blockIdx.x * 4 + wave;
    if (h >= H) return;
    const int lane = threadIdx.x & 63;
    const int half = lane >> 5;
    const int col  = (lane & 31) << 2;   // dims col..col+3

    const int start = off[h];
    const int end   = off[h + 1];

    f4 acc = {0.f, 0.f, 0.f, 0.f};

    for (int base = start; base < end; base += 64) {
        const int nchunk = min(end - base, 64);
        const int myidx =
            __builtin_nontemporal_load(node_idx + base + min(lane, nchunk - 1));

        for (int j = 0; j < nchunk; j += 32) {
            uint2 v[16];
#pragma unroll
            for (int k = 0; k < 16; ++k) {
                const int ik = __shfl(myidx, min(j + 2 * k + half, nchunk - 1), 64);
                v[k] = *(const uint2*)(table + (size_t)ik * D + col);
            }
#pragma unroll
            for (int k = 0; k < 16; ++k) {
                if (j + 2 * k + half < nchunk) {
                    acc.x += bf16_lo(v[k].x); acc.y += bf16_hi(v[k].x);
                    acc.z += bf16_lo(v[k].y); acc.w += bf16_hi(v[k].y);
                }
            }
        }
    }

    acc.x += __shfl_xor(acc.x, 32, 64);
    acc.y += __shfl_xor(acc.y, 32, 64);
    acc.z += __shfl_xor(acc.z, 32, 64);
    acc.w += __shfl_xor(acc.w, 32, 64);

    if (half == 0) {
        const int cnt = end - start;
        const float inv = 1.0f / (float)(cnt > 0 ? cnt : 1);
        f4 r = acc * inv;
        __builtin_nontemporal_store(r, (f4*)(out + (size_t)h * D + col));
    }
}

// Fallback (no workspace for the bf16 table): R4 fp32 gather.
__global__ __launch_bounds__(256)
void seg_offsets_kernel(const int* __restrict__ seg, int E, int H,
                        int* __restrict__ off) {
    const int e = blockIdx.x * blockDim.x + threadIdx.x;
    if (e >= E) return;
    const int s = seg[e];
    const int prev = (e == 0) ? -1 : seg[e - 1];
    for (int h = prev + 1; h <= s; ++h) off[h] = e;
    if (e == E - 1) {
        for (int h = s + 1; h <= H; ++h) off[h] = E;
    }
}

__global__ __launch_bounds__(256)
void hyperedge_mean_f32(const float* __restrict__ embed,
                        const int* __restrict__ node_idx,
                        const int* __restrict__ off,
                        float* __restrict__ out,
                        int H) {
    const int wave = threadIdx.x >> 6;
    const int h    = blockIdx.x * 4 + wave;
    if (h >= H) return;
    const int lane = threadIdx.x & 63;
    const int half = lane >> 5;
    const int col  = (lane & 31) << 2;

    const int start = off[h];
    const int end   = off[h + 1];

    f4 acc = {0.f, 0.f, 0.f, 0.f};

    for (int base = start; base < end; base += 64) {
        const int nchunk = min(end - base, 64);
        const int myidx =
            __builtin_nontemporal_load(node_idx + base + min(lane, nchunk - 1));
        for (int j = 0; j < nchunk; j += 16) {
            f4 v[8];
#pragma unroll
            for (int k = 0; k < 8; ++k) {
                const int ik = __shfl(myidx, min(j + 2 * k + half, nchunk - 1), 64);
                v[k] = *(const f4*)(embed + (size_t)ik * D + col);
            }
#pragma unroll
            for (int k = 0; k < 8; ++k) {
                if (j + 2 * k + half < nchunk) acc += v[k];
            }
        }
    }

    acc.x += __shfl_xor(acc.x, 32, 64);
    acc.y += __shfl_xor(acc.y, 32, 64);
    acc.z += __shfl_xor(acc.z, 32, 64);
    acc.w += __shfl_xor(acc.w, 32, 64);

    if (half == 0) {
        const int cnt = end - start;
        const float inv = 1.0f / (float)(cnt > 0 ? cnt : 1);
        f4 r = acc * inv;
        __builtin_nontemporal_store(r, (f4*)(out + (size_t)h * D + col));
    }
}

extern "C" void kernel_launch(void* const* d_in, const int* in_sizes, int n_in,
                              void* d_out, int out_size, void* d_ws, size_t ws_size,
                              hipStream_t stream) {
    const float* embed    = (const float*)d_in[0];
    const int*   node_idx = (const int*)d_in[1];
    const int*   seg_ids  = (const int*)d_in[2];
    float*       out      = (float*)d_out;

    const int Ntab = in_sizes[0];       // table elements (nodes * D)
    const int E    = in_sizes[1];       // total incidence entries
    const int H    = out_size / D;      // number of hyperedges

    int* off = (int*)d_ws;              // (H+1) ints
    const size_t off_bytes  = ((size_t)(H + 1) * 4 + 255) & ~(size_t)255;
    const size_t bf16_bytes = (size_t)Ntab * 2;

    if (ws_size >= off_bytes + bf16_bytes) {
        unsigned short* table = (unsigned short*)((char*)d_ws + off_bytes);
        const int n4     = Ntab / 4;
        const int nb_cvt = (n4 + 255) / 256;
        const int nb_off = (E + 255) / 256;
        prologue_kernel<<<dim3(nb_cvt + nb_off), dim3(256), 0, stream>>>(
            embed, table, n4, nb_cvt, seg_ids, E, H, off);
        hyperedge_mean_bf16<<<dim3((H + 3) / 4), dim3(256), 0, stream>>>(
            table, node_idx, off, out, H);
    } else {
        seg_offsets_kernel<<<dim3((E + 255) / 256), dim3(256), 0, stream>>>(
            seg_ids, E, H, off);
        hyperedge_mean_f32<<<dim3((H + 3) / 4), dim3(256), 0, stream>>>(
            embed, node_idx, off, out, H);
    }
}

// Round 8
// 230.424 us; speedup vs baseline: 1.0099x; 1.0099x over previous
//
#include <hip/hip_runtime.h>

// HyperedgeMeanAggregator: out[h,:] = mean of embed[node_idx[e],:] over the
// contiguous run of entries e with seg_ids[e]==h (seg_ids sorted).
//
// Round 8 = R5's proven gather loop (8-wide, 28 VGPR) + R7's fused prologue.
// Model (validated R5, re-confirmed R7):
//   time(gather) = random-128B-line fetch volume / ~3.3 TB/s
//   bf16 staging halves volume (FETCH 390 -> 190 MB, 130 -> 60.5 us).
//   R7's 16-wide unroll REGRESSED (70.8 us: VGPR 36, one vmcnt drain per 32
//   entries) -> keep the 8-wide shape.
//   fp8 staging infeasible: absmax ~ 2*eps -> ~0.125 > 0.0209 threshold.

#define D 128

typedef float f4 __attribute__((ext_vector_type(4)));
typedef unsigned short us4 __attribute__((ext_vector_type(4)));

// Fused prologue: blocks [0, nb_cvt) convert fp32->bf16 (4 elems/thread);
// blocks [nb_cvt, nb_cvt+nb_off) compute segment offsets. Independent work.
__global__ __launch_bounds__(256)
void prologue_kernel(const float* __restrict__ src,
                     unsigned short* __restrict__ dst, int n4, int nb_cvt,
                     const int* __restrict__ seg, int E, int H,
                     int* __restrict__ off) {
    if ((int)blockIdx.x < nb_cvt) {
        const int i = blockIdx.x * 256 + threadIdx.x;
        if (i >= n4) return;
        const f4 v = ((const f4*)src)[i];
        union { float f; unsigned u; } c;
        us4 r;
#define CVT(K, X) c.f = (X); \
        r[K] = (unsigned short)((c.u + 0x7fffu + ((c.u >> 16) & 1u)) >> 16);
        CVT(0, v.x) CVT(1, v.y) CVT(2, v.z) CVT(3, v.w)
#undef CVT
        __builtin_nontemporal_store(r, (us4*)dst + i);
    } else {
        const int e = (blockIdx.x - nb_cvt) * 256 + threadIdx.x;
        if (e >= E) return;
        const int s = seg[e];
        const int prev = (e == 0) ? -1 : seg[e - 1];
        for (int h = prev + 1; h <= s; ++h) off[h] = e;
        if (e == E - 1) {
            for (int h = s + 1; h <= H; ++h) off[h] = E;
        }
    }
}

__device__ __forceinline__ float bf16_lo(unsigned u) {
    union { unsigned u; float f; } c; c.u = u << 16; return c.f;
}
__device__ __forceinline__ float bf16_hi(unsigned u) {
    union { unsigned u; float f; } c; c.u = u & 0xffff0000u; return c.f;
}

// Main gather over the bf16 staged table. One wave per segment.
// lane&31 owns bf16 dims [4c..4c+3] (uint2 = 8B); 32 lanes x 8B = 256B = one
// row = exactly 2 cache lines; lane>>5 picks which of 2 rows per load instr;
// 8 load instrs = 16 entries in flight per wave (R5's proven shape).
__global__ __launch_bounds__(256)
void hyperedge_mean_bf16(const unsigned short* __restrict__ table,
                         const int* __restrict__ node_idx,
                         const int* __restrict__ off,
                         float* __restrict__ out,
                         int H) {
    const int wave = threadIdx.x >> 6;
    const int h    = blockIdx.x * 4 + wave;
    if (h >= H) return;
    const int lane = threadIdx.x & 63;
    const int half = lane >> 5;
    const int col  = (lane & 31) << 2;   // dims col..col+3

    const int start = off[h];
    const int end   = off[h + 1];

    f4 acc = {0.f, 0.f, 0.f, 0.f};

    for (int base = start; base < end; base += 64) {
        const int nchunk = min(end - base, 64);
        const int myidx =
            __builtin_nontemporal_load(node_idx + base + min(lane, nchunk - 1));

        for (int j = 0; j < nchunk; j += 16) {
            const int i0 = __shfl(myidx, min(j +  0 + half, nchunk - 1), 64);
            const int i1 = __shfl(myidx, min(j +  2 + half, nchunk - 1), 64);
            const int i2 = __shfl(myidx, min(j +  4 + half, nchunk - 1), 64);
            const int i3 = __shfl(myidx, min(j +  6 + half, nchunk - 1), 64);
            const int i4 = __shfl(myidx, min(j +  8 + half, nchunk - 1), 64);
            const int i5 = __shfl(myidx, min(j + 10 + half, nchunk - 1), 64);
            const int i6 = __shfl(myidx, min(j + 12 + half, nchunk - 1), 64);
            const int i7 = __shfl(myidx, min(j + 14 + half, nchunk - 1), 64);

            const uint2 v0 = *(const uint2*)(table + (size_t)i0 * D + col);
            const uint2 v1 = *(const uint2*)(table + (size_t)i1 * D + col);
            const uint2 v2 = *(const uint2*)(table + (size_t)i2 * D + col);
            const uint2 v3 = *(const uint2*)(table + (size_t)i3 * D + col);
            const uint2 v4 = *(const uint2*)(table + (size_t)i4 * D + col);
            const uint2 v5 = *(const uint2*)(table + (size_t)i5 * D + col);
            const uint2 v6 = *(const uint2*)(table + (size_t)i6 * D + col);
            const uint2 v7 = *(const uint2*)(table + (size_t)i7 * D + col);

#define ACCUM(K, V)                                                      \
            if (j + 2 * (K) + half < nchunk) {                           \
                acc.x += bf16_lo((V).x); acc.y += bf16_hi((V).x);        \
                acc.z += bf16_lo((V).y); acc.w += bf16_hi((V).y);        \
            }
            ACCUM(0, v0) ACCUM(1, v1) ACCUM(2, v2) ACCUM(3, v3)
            ACCUM(4, v4) ACCUM(5, v5) ACCUM(6, v6) ACCUM(7, v7)
#undef ACCUM
        }
    }

    acc.x += __shfl_xor(acc.x, 32, 64);
    acc.y += __shfl_xor(acc.y, 32, 64);
    acc.z += __shfl_xor(acc.z, 32, 64);
    acc.w += __shfl_xor(acc.w, 32, 64);

    if (half == 0) {
        const int cnt = end - start;
        const float inv = 1.0f / (float)(cnt > 0 ? cnt : 1);
        f4 r = acc * inv;
        __builtin_nontemporal_store(r, (f4*)(out + (size_t)h * D + col));
    }
}

// Fallback (no workspace for the bf16 table): R4 fp32 gather.
__global__ __launch_bounds__(256)
void seg_offsets_kernel(const int* __restrict__ seg, int E, int H,
                        int* __restrict__ off) {
    const int e = blockIdx.x * blockDim.x + threadIdx.x;
    if (e >= E) return;
    const int s = seg[e];
    const int prev = (e == 0) ? -1 : seg[e - 1];
    for (int h = prev + 1; h <= s; ++h) off[h] = e;
    if (e == E - 1) {
        for (int h = s + 1; h <= H; ++h) off[h] = E;
    }
}

__global__ __launch_bounds__(256)
void hyperedge_mean_f32(const float* __restrict__ embed,
                        const int* __restrict__ node_idx,
                        const int* __restrict__ off,
                        float* __restrict__ out,
                        int H) {
    const int wave = threadIdx.x >> 6;
    const int h    = blockIdx.x * 4 + wave;
    if (h >= H) return;
    const int lane = threadIdx.x & 63;
    const int half = lane >> 5;
    const int col  = (lane & 31) << 2;

    const int start = off[h];
    const int end   = off[h + 1];

    f4 acc = {0.f, 0.f, 0.f, 0.f};

    for (int base = start; base < end; base += 64) {
        const int nchunk = min(end - base, 64);
        const int myidx =
            __builtin_nontemporal_load(node_idx + base + min(lane, nchunk - 1));
        for (int j = 0; j < nchunk; j += 16) {
            f4 v[8];
#pragma unroll
            for (int k = 0; k < 8; ++k) {
                const int ik = __shfl(myidx, min(j + 2 * k + half, nchunk - 1), 64);
                v[k] = *(const f4*)(embed + (size_t)ik * D + col);
            }
#pragma unroll
            for (int k = 0; k < 8; ++k) {
                if (j + 2 * k + half < nchunk) acc += v[k];
            }
        }
    }

    acc.x += __shfl_xor(acc.x, 32, 64);
    acc.y += __shfl_xor(acc.y, 32, 64);
    acc.z += __shfl_xor(acc.z, 32, 64);
    acc.w += __shfl_xor(acc.w, 32, 64);

    if (half == 0) {
        const int cnt = end - start;
        const float inv = 1.0f / (float)(cnt > 0 ? cnt : 1);
        f4 r = acc * inv;
        __builtin_nontemporal_store(r, (f4*)(out + (size_t)h * D + col));
    }
}

extern "C" void kernel_launch(void* const* d_in, const int* in_sizes, int n_in,
                              void* d_out, int out_size, void* d_ws, size_t ws_size,
                              hipStream_t stream) {
    const float* embed    = (const float*)d_in[0];
    const int*   node_idx = (const int*)d_in[1];
    const int*   seg_ids  = (const int*)d_in[2];
    float*       out      = (float*)d_out;

    const int Ntab = in_sizes[0];       // table elements (nodes * D)
    const int E    = in_sizes[1];       // total incidence entries
    const int H    = out_size / D;      // number of hyperedges

    int* off = (int*)d_ws;              // (H+1) ints
    const size_t off_bytes  = ((size_t)(H + 1) * 4 + 255) & ~(size_t)255;
    const size_t bf16_bytes = (size_t)Ntab * 2;

    if (ws_size >= off_bytes + bf16_bytes) {
        unsigned short* table = (unsigned short*)((char*)d_ws + off_bytes);
        const int n4     = Ntab / 4;
        const int nb_cvt = (n4 + 255) / 256;
        const int nb_off = (E + 255) / 256;
        prologue_kernel<<<dim3(nb_cvt + nb_off), dim3(256), 0, stream>>>(
            embed, table, n4, nb_cvt, seg_ids, E, H, off);
        hyperedge_mean_bf16<<<dim3((H + 3) / 4), dim3(256), 0, stream>>>(
            table, node_idx, off, out, H);
    } else {
        seg_offsets_kernel<<<dim3((E + 255) / 256), dim3(256), 0, stream>>>(
            seg_ids, E, H, off);
        hyperedge_mean_f32<<<dim3((H + 3) / 4), dim3(256), 0, stream>>>(
            embed, node_idx, off, out, H);
    }
}